// Round 1
// baseline (221.152 us; speedup 1.0000x reference)
//
#include <hip/hip_runtime.h>
#include <math.h>

#define TOKENS 16384
#define HIDDEN 2048
#define BM 128
#define BN 128
#define BK 32

typedef __attribute__((ext_vector_type(4))) float f32x4;
typedef __attribute__((ext_vector_type(8))) short s16x8;

__device__ __forceinline__ unsigned short f2bf(float f) {
  unsigned int u = __float_as_uint(f);
  u += 0x7fffu + ((u >> 16) & 1u);   // round-to-nearest-even
  return (unsigned short)(u >> 16);
}

// ---------------- kernel 0: W fp32 -> bf16 ----------------
__global__ __launch_bounds__(256) void wconv_kernel(const float* __restrict__ W,
                                                    unsigned short* __restrict__ Wb) {
  const int n4 = (HIDDEN * HIDDEN) / 4;
  for (int i = blockIdx.x * 256 + threadIdx.x; i < n4; i += gridDim.x * 256) {
    float4 v = *(const float4*)(W + (size_t)i * 4);
    ushort4 o;
    o.x = f2bf(v.x); o.y = f2bf(v.y); o.z = f2bf(v.z); o.w = f2bf(v.w);
    *(ushort4*)(Wb + (size_t)i * 4) = o;
  }
}

// ---------------- kernel 1: LayerNorm fp32 -> bf16, one block per row ----------------
__global__ __launch_bounds__(256) void ln_kernel(const float* __restrict__ x,
                                                 const float* __restrict__ gamma,
                                                 const float* __restrict__ beta,
                                                 unsigned short* __restrict__ xn) {
  const int row = blockIdx.x;
  const int t = threadIdx.x;
  const int wave = t >> 6, lane = t & 63;
  const float* xr = x + (size_t)row * HIDDEN + t * 8;
  float4 v0 = *(const float4*)(xr);
  float4 v1 = *(const float4*)(xr + 4);
  float xv[8] = {v0.x, v0.y, v0.z, v0.w, v1.x, v1.y, v1.z, v1.w};

  float s = 0.f, ss = 0.f;
#pragma unroll
  for (int j = 0; j < 8; ++j) { s += xv[j]; ss = fmaf(xv[j], xv[j], ss); }

#pragma unroll
  for (int off = 32; off > 0; off >>= 1) {
    s += __shfl_xor(s, off, 64);
    ss += __shfl_xor(ss, off, 64);
  }
  __shared__ float rs[4], rss[4];
  if (lane == 0) { rs[wave] = s; rss[wave] = ss; }
  __syncthreads();
  s = rs[0] + rs[1] + rs[2] + rs[3];
  ss = rss[0] + rss[1] + rss[2] + rss[3];

  const float mean = s * (1.0f / HIDDEN);
  const float var = ss * (1.0f / HIDDEN) - mean * mean;
  const float rstd = rsqrtf(var + 1e-5f);

  float4 g0 = *(const float4*)(gamma + t * 8);
  float4 g1 = *(const float4*)(gamma + t * 8 + 4);
  float4 b0 = *(const float4*)(beta + t * 8);
  float4 b1 = *(const float4*)(beta + t * 8 + 4);
  float gv[8] = {g0.x, g0.y, g0.z, g0.w, g1.x, g1.y, g1.z, g1.w};
  float bv[8] = {b0.x, b0.y, b0.z, b0.w, b1.x, b1.y, b1.z, b1.w};

  union { unsigned short h[8]; uint4 q; } pk;
#pragma unroll
  for (int j = 0; j < 8; ++j)
    pk.h[j] = f2bf((xv[j] - mean) * rstd * gv[j] + bv[j]);
  *(uint4*)(xn + (size_t)row * HIDDEN + t * 8) = pk.q;
}

// ---------------- kernel 2: bf16 GEMM (A[M,K] * B[N,K]^T) + bias + exact GELU ----------------
// m97 structure: 128x128 tile, BK=32, 4 waves, 4x4 fragments of 16x16x32 bf16 MFMA,
// global_load_lds width=16 staging, 2 barriers per K-step, XCD-aware swizzle.
__global__ __launch_bounds__(256) void gemm_kernel(const unsigned short* __restrict__ A,
                                                   const unsigned short* __restrict__ B,
                                                   const float* __restrict__ bias,
                                                   float* __restrict__ out) {
  __shared__ short As[BM * BK];   // 8 KB, row-major [128][32]
  __shared__ short Bs[BN * BK];   // 8 KB, row-major [128][32]

  const int tid = threadIdx.x;
  const int wave = tid >> 6, lane = tid & 63;

  // XCD swizzle: gridDim.x = 2048, divisible by 8 -> simple bijective remap
  const int wg = blockIdx.x;
  const int swz = (wg & 7) * (gridDim.x >> 3) + (wg >> 3);
  const int tm = swz >> 4;   // 0..127 (M tiles: 16384/128)
  const int tn = swz & 15;   // 0..15  (N tiles: 2048/128)
  const int row0 = tm * BM, col0 = tn * BN;

  // staging geometry: per wave, 2 chunks of 1 KB each for A and B.
  // LDS dest is wave-uniform base; HW writes lane l at base + l*16B.
  // lane l of chunk (wave*2+i) covers tile row (wave*2+i)*16 + l/4, k-bytes (l%4)*16.
  const int stage_c = (lane & 3) * 8;          // k element offset (8 bf16 = 16B)
  const int stage_r0 = (wave * 2) * 16 + (lane >> 2);
  const int stage_r1 = (wave * 2 + 1) * 16 + (lane >> 2);

  const unsigned short* gA0 = A + (size_t)(row0 + stage_r0) * HIDDEN + stage_c;
  const unsigned short* gA1 = A + (size_t)(row0 + stage_r1) * HIDDEN + stage_c;
  const unsigned short* gB0 = B + (size_t)(col0 + stage_r0) * HIDDEN + stage_c;
  const unsigned short* gB1 = B + (size_t)(col0 + stage_r1) * HIDDEN + stage_c;

  const int wm = (wave >> 1) * 64;  // wave's M offset in tile
  const int wn = (wave & 1) * 64;   // wave's N offset in tile
  const int kb = (lane >> 4) * 8;   // fragment k base (lane-group * 8)
  const int fr = lane & 15;         // fragment row/col within 16

  f32x4 acc[4][4] = {};

  for (int k0 = 0; k0 < HIDDEN; k0 += BK) {
    // ---- stage A,B tiles into LDS (async, direct-to-LDS) ----
    __builtin_amdgcn_global_load_lds(
        (const __attribute__((address_space(1))) unsigned int*)(gA0 + k0),
        (__attribute__((address_space(3))) unsigned int*)&As[(wave * 2) * 512], 16, 0, 0);
    __builtin_amdgcn_global_load_lds(
        (const __attribute__((address_space(1))) unsigned int*)(gA1 + k0),
        (__attribute__((address_space(3))) unsigned int*)&As[(wave * 2 + 1) * 512], 16, 0, 0);
    __builtin_amdgcn_global_load_lds(
        (const __attribute__((address_space(1))) unsigned int*)(gB0 + k0),
        (__attribute__((address_space(3))) unsigned int*)&Bs[(wave * 2) * 512], 16, 0, 0);
    __builtin_amdgcn_global_load_lds(
        (const __attribute__((address_space(1))) unsigned int*)(gB1 + k0),
        (__attribute__((address_space(3))) unsigned int*)&Bs[(wave * 2 + 1) * 512], 16, 0, 0);
    __syncthreads();   // compiler emits vmcnt(0)+lgkmcnt(0) drain before s_barrier

    // ---- LDS -> fragments (ds_read_b128 each) ----
    s16x8 af[4], bf[4];
#pragma unroll
    for (int mi = 0; mi < 4; ++mi)
      af[mi] = *(const s16x8*)&As[(wm + mi * 16 + fr) * BK + kb];
#pragma unroll
    for (int ni = 0; ni < 4; ++ni)
      bf[ni] = *(const s16x8*)&Bs[(wn + ni * 16 + fr) * BK + kb];

    // ---- 16 MFMA ----
#pragma unroll
    for (int mi = 0; mi < 4; ++mi)
#pragma unroll
      for (int ni = 0; ni < 4; ++ni)
        acc[mi][ni] = __builtin_amdgcn_mfma_f32_16x16x32_bf16(af[mi], bf[ni], acc[mi][ni], 0, 0, 0);
    __syncthreads();   // protect LDS before next stage overwrites
  }

  // ---- epilogue: bias + exact GELU, fp32 store ----
  // C/D layout (verified m89/m91): col = lane&15, row = (lane>>4)*4 + j
  float bcol[4];
#pragma unroll
  for (int ni = 0; ni < 4; ++ni)
    bcol[ni] = bias[col0 + wn + ni * 16 + fr];

#pragma unroll
  for (int mi = 0; mi < 4; ++mi) {
#pragma unroll
    for (int ni = 0; ni < 4; ++ni) {
      const int c = col0 + wn + ni * 16 + fr;
#pragma unroll
      for (int j = 0; j < 4; ++j) {
        const int r = row0 + wm + mi * 16 + (lane >> 4) * 4 + j;
        float y = acc[mi][ni][j] + bcol[ni];
        out[(size_t)r * HIDDEN + c] = 0.5f * y * (1.0f + erff(y * 0.70710678118654752f));
      }
    }
  }
}

extern "C" void kernel_launch(void* const* d_in, const int* in_sizes, int n_in,
                              void* d_out, int out_size, void* d_ws, size_t ws_size,
                              hipStream_t stream) {
  const float* x     = (const float*)d_in[0];
  const float* gamma = (const float*)d_in[1];
  const float* beta  = (const float*)d_in[2];
  const float* W     = (const float*)d_in[3];
  const float* bias  = (const float*)d_in[4];
  float* out = (float*)d_out;

  // workspace layout: xn bf16 [16384*2048] = 64 MB, then W bf16 [2048*2048] = 8 MB
  unsigned short* xn = (unsigned short*)d_ws;
  unsigned short* wb = (unsigned short*)((char*)d_ws + (size_t)TOKENS * HIDDEN * 2);

  hipLaunchKernelGGL(wconv_kernel, dim3(1024), dim3(256), 0, stream, W, wb);
  hipLaunchKernelGGL(ln_kernel, dim3(TOKENS), dim3(256), 0, stream, x, gamma, beta, xn);
  hipLaunchKernelGGL(gemm_kernel, dim3((TOKENS / BM) * (HIDDEN / BN)), dim3(256), 0, stream,
                     xn, wb, bias, out);
}

// Round 2
// 188.760 us; speedup vs baseline: 1.1716x; 1.1716x over previous
//
#include <hip/hip_runtime.h>
#include <math.h>

#define TOKENS 16384
#define HIDDEN 2048
#define BM 256
#define BN 256
#define BK 64
#define NT (HIDDEN / BK)   // 32 K-tiles

typedef __attribute__((ext_vector_type(4))) float f32x4;
typedef __attribute__((ext_vector_type(8))) short s16x8;

__device__ __forceinline__ unsigned short f2bf(float f) {
  unsigned int u = __float_as_uint(f);
  u += 0x7fffu + ((u >> 16) & 1u);   // round-to-nearest-even
  return (unsigned short)(u >> 16);
}

// ---------------- kernel 0: W fp32 -> bf16 ----------------
__global__ __launch_bounds__(256) void wconv_kernel(const float* __restrict__ W,
                                                    unsigned short* __restrict__ Wb) {
  const int n4 = (HIDDEN * HIDDEN) / 4;
  for (int i = blockIdx.x * 256 + threadIdx.x; i < n4; i += gridDim.x * 256) {
    float4 v = *(const float4*)(W + (size_t)i * 4);
    ushort4 o;
    o.x = f2bf(v.x); o.y = f2bf(v.y); o.z = f2bf(v.z); o.w = f2bf(v.w);
    *(ushort4*)(Wb + (size_t)i * 4) = o;
  }
}

// ---------------- kernel 1: LayerNorm fp32 -> bf16, one block per row ----------------
__global__ __launch_bounds__(256) void ln_kernel(const float* __restrict__ x,
                                                 const float* __restrict__ gamma,
                                                 const float* __restrict__ beta,
                                                 unsigned short* __restrict__ xn) {
  const int row = blockIdx.x;
  const int t = threadIdx.x;
  const int wave = t >> 6, lane = t & 63;
  const float* xr = x + (size_t)row * HIDDEN + t * 8;
  float4 v0 = *(const float4*)(xr);
  float4 v1 = *(const float4*)(xr + 4);
  float xv[8] = {v0.x, v0.y, v0.z, v0.w, v1.x, v1.y, v1.z, v1.w};

  float s = 0.f, ss = 0.f;
#pragma unroll
  for (int j = 0; j < 8; ++j) { s += xv[j]; ss = fmaf(xv[j], xv[j], ss); }

#pragma unroll
  for (int off = 32; off > 0; off >>= 1) {
    s += __shfl_xor(s, off, 64);
    ss += __shfl_xor(ss, off, 64);
  }
  __shared__ float rs[4], rss[4];
  if (lane == 0) { rs[wave] = s; rss[wave] = ss; }
  __syncthreads();
  s = rs[0] + rs[1] + rs[2] + rs[3];
  ss = rss[0] + rss[1] + rss[2] + rss[3];

  const float mean = s * (1.0f / HIDDEN);
  const float var = ss * (1.0f / HIDDEN) - mean * mean;
  const float rstd = rsqrtf(var + 1e-5f);

  float4 g0 = *(const float4*)(gamma + t * 8);
  float4 g1 = *(const float4*)(gamma + t * 8 + 4);
  float4 b0 = *(const float4*)(beta + t * 8);
  float4 b1 = *(const float4*)(beta + t * 8 + 4);
  float gv[8] = {g0.x, g0.y, g0.z, g0.w, g1.x, g1.y, g1.z, g1.w};
  float bv[8] = {b0.x, b0.y, b0.z, b0.w, b1.x, b1.y, b1.z, b1.w};

  union { unsigned short h[8]; uint4 q; } pk;
#pragma unroll
  for (int j = 0; j < 8; ++j)
    pk.h[j] = f2bf((xv[j] - mean) * rstd * gv[j] + bv[j]);
  *(uint4*)(xn + (size_t)row * HIDDEN + t * 8) = pk.q;
}

// ---------------- kernel 2: 256x256 8-phase bf16 GEMM + bias + exact GELU ----------------
// A[M,K] * B[N,K]^T. 512 threads = 8 waves (2M x 4N), per-wave output 128x64.
// LDS 128 KiB: 2 buf x {A,B} x 2 half x 2 quarter x 8KB. Quarter = 64 rows x 64 cols bf16.
// XOR swizzle byte ^= ((row&7)<<4) applied on global-gather side AND ds_read side.
// Counted vmcnt(4) once per K-tile; raw s_barrier; setprio around MFMA clusters.

#define GLOAD(gp, lp) __builtin_amdgcn_global_load_lds( \
    (const __attribute__((address_space(1))) unsigned int*)(gp), \
    (__attribute__((address_space(3))) unsigned int*)(lp), 16, 0, 0)

__global__ __launch_bounds__(512, 1) void gemm_kernel(const unsigned short* __restrict__ A,
                                                      const unsigned short* __restrict__ B,
                                                      const float* __restrict__ bias,
                                                      float* __restrict__ out) {
  __shared__ __attribute__((aligned(16))) char lds[131072];

  const int tid = threadIdx.x;
  const int lane = tid & 63;
  const int wave = tid >> 6;
  const int fr = lane & 15, hi = lane >> 4;

  // XCD-aware swizzle: 512 WGs, 512 % 8 == 0 -> bijective
  const int wg = blockIdx.x;
  const int swz = (wg & 7) * 64 + (wg >> 3);
  const int tm = swz >> 3, tn = swz & 7;   // 64 M-tiles x 8 N-tiles
  const int row0 = tm * BM, col0 = tn * BN;

  const int wmi = wave >> 2;        // wave M index (0..1)
  const int wni = wave & 3;         // wave N index (0..3)
  const int hB = wni >> 1, gB = wni & 1;

  // ---- staging geometry (per-lane gather, pre-swizzled source) ----
  // lane tid: rho = tid>>3 (row in quarter), sig = tid&7 (16B slot). LDS write is linear
  // (lane*16); source column group is sig ^ (rho&7) so that reads can XOR-deswizzle.
  const int rho = tid >> 3, sig = tid & 7;
  const int colgrp = ((sig ^ (rho & 7)) << 3);                 // k-element offset
  const unsigned short* Ap = A + (size_t)(row0 + rho) * HIDDEN + colgrp;
  const unsigned short* Bp = B + (size_t)(col0 + ((rho >> 5) << 6) + (rho & 31)) * HIDDEN + colgrp;
  const int ldsWaveOff = wave << 10;                            // 64 lanes * 16B

  // ---- ds_read per-lane constants (swizzled slot bytes for kk=0,1) ----
  const int s0 = ((hi ^ (fr & 7)) << 4);
  const int s1 = (((4 + hi) ^ (fr & 7)) << 4);
  const int aRowB = fr << 7;                        // fr*128
  const int bRowB = (((gB << 5) + fr) << 7);        // (gB*32+fr)*128

  auto stageA = [&](int tt, int bufd, int qm) {     // 2 calls: halves h=0,1 of quarter qm
    const int tc = tt < NT ? tt : NT - 1;
    const unsigned short* g = Ap + (size_t)(qm << 6) * HIDDEN + tc * BK;
    GLOAD(g, lds + ((((bufd << 2) | qm) << 13)) + ldsWaveOff);
    GLOAD(g + (size_t)128 * HIDDEN, lds + ((((bufd << 2) | 2 | qm) << 13)) + ldsWaveOff);
  };
  auto stageB = [&](int tt, int bufd, int qn) {
    const int tc = tt < NT ? tt : NT - 1;
    const unsigned short* g = Bp + (size_t)(qn << 5) * HIDDEN + tc * BK;
    GLOAD(g, lds + 65536 + ((((bufd << 2) | qn) << 13)) + ldsWaveOff);
    GLOAD(g + (size_t)128 * HIDDEN, lds + 65536 + ((((bufd << 2) | 2 | qn) << 13)) + ldsWaveOff);
  };

  f32x4 acc[2][4][4] = {};
  s16x8 a[4][2], b[2][2];

  // ---- prologue: tile0 fully + tile1's first 2 quarters, in steady-state age order ----
  stageA(0, 0, 0); stageB(0, 0, 1); stageA(0, 0, 1); stageB(0, 0, 0);
  stageA(1, 1, 0); stageB(1, 1, 1);
  asm volatile("s_waitcnt vmcnt(4)" ::: "memory");   // tile0's 8 calls landed
  __builtin_amdgcn_s_barrier();

  for (int t = 0; t < NT; ++t) {
    const int buf = t & 1;
    const char* Abase = lds + (((buf << 2) | (wmi << 1)) << 13);
    const char* Bbase = lds + 65536 + (((buf << 2) | (hB << 1)) << 13);

    // ===== p0: quadrant (qm=0, qn=0) =====
#pragma unroll
    for (int mi = 0; mi < 4; ++mi) {
      a[mi][0] = *(const s16x8*)(Abase + mi * 2048 + aRowB + s0);
      a[mi][1] = *(const s16x8*)(Abase + mi * 2048 + aRowB + s1);
    }
#pragma unroll
    for (int nj = 0; nj < 2; ++nj) {
      b[nj][0] = *(const s16x8*)(Bbase + nj * 2048 + bRowB + s0);
      b[nj][1] = *(const s16x8*)(Bbase + nj * 2048 + bRowB + s1);
    }
    stageA(t + 1, buf ^ 1, 1);
    asm volatile("s_waitcnt lgkmcnt(8)" ::: "memory");
    __builtin_amdgcn_s_barrier();
    asm volatile("s_waitcnt lgkmcnt(0)" ::: "memory");
    __builtin_amdgcn_s_setprio(1);
#pragma unroll
    for (int mi = 0; mi < 4; ++mi)
#pragma unroll
      for (int nj = 0; nj < 2; ++nj)
#pragma unroll
        for (int kk = 0; kk < 2; ++kk)
          acc[0][mi][nj] = __builtin_amdgcn_mfma_f32_16x16x32_bf16(a[mi][kk], b[nj][kk], acc[0][mi][nj], 0, 0, 0);
    __builtin_amdgcn_s_setprio(0);
    __builtin_amdgcn_s_barrier();

    // ===== p1: quadrant (qm=0, qn=1) — reuse a =====
#pragma unroll
    for (int nj = 0; nj < 2; ++nj) {
      b[nj][0] = *(const s16x8*)(Bbase + 8192 + nj * 2048 + bRowB + s0);
      b[nj][1] = *(const s16x8*)(Bbase + 8192 + nj * 2048 + bRowB + s1);
    }
    stageB(t + 1, buf ^ 1, 0);
    __builtin_amdgcn_s_barrier();
    asm volatile("s_waitcnt lgkmcnt(0)" ::: "memory");
    __builtin_amdgcn_s_setprio(1);
#pragma unroll
    for (int mi = 0; mi < 4; ++mi)
#pragma unroll
      for (int nj = 0; nj < 2; ++nj)
#pragma unroll
        for (int kk = 0; kk < 2; ++kk)
          acc[0][mi][2 + nj] = __builtin_amdgcn_mfma_f32_16x16x32_bf16(a[mi][kk], b[nj][kk], acc[0][mi][2 + nj], 0, 0, 0);
    __builtin_amdgcn_s_setprio(0);
    __builtin_amdgcn_s_barrier();

    // ===== p2: quadrant (qm=1, qn=1) — reuse b =====
#pragma unroll
    for (int mi = 0; mi < 4; ++mi) {
      a[mi][0] = *(const s16x8*)(Abase + 8192 + mi * 2048 + aRowB + s0);
      a[mi][1] = *(const s16x8*)(Abase + 8192 + mi * 2048 + aRowB + s1);
    }
    stageA(t + 2, buf, 0);
    __builtin_amdgcn_s_barrier();
    asm volatile("s_waitcnt lgkmcnt(0)" ::: "memory");
    __builtin_amdgcn_s_setprio(1);
#pragma unroll
    for (int mi = 0; mi < 4; ++mi)
#pragma unroll
      for (int nj = 0; nj < 2; ++nj)
#pragma unroll
        for (int kk = 0; kk < 2; ++kk)
          acc[1][mi][2 + nj] = __builtin_amdgcn_mfma_f32_16x16x32_bf16(a[mi][kk], b[nj][kk], acc[1][mi][2 + nj], 0, 0, 0);
    __builtin_amdgcn_s_setprio(0);
    __builtin_amdgcn_s_barrier();

    // ===== p3: quadrant (qm=1, qn=0) — reuse a; K-tile boundary vmcnt =====
#pragma unroll
    for (int nj = 0; nj < 2; ++nj) {
      b[nj][0] = *(const s16x8*)(Bbase + nj * 2048 + bRowB + s0);
      b[nj][1] = *(const s16x8*)(Bbase + nj * 2048 + bRowB + s1);
    }
    stageB(t + 2, buf, 1);
    asm volatile("s_waitcnt vmcnt(4)" ::: "memory");   // counted: next tile fully landed, 4 in flight
    __builtin_amdgcn_s_barrier();
    asm volatile("s_waitcnt lgkmcnt(0)" ::: "memory");
    __builtin_amdgcn_s_setprio(1);
#pragma unroll
    for (int mi = 0; mi < 4; ++mi)
#pragma unroll
      for (int nj = 0; nj < 2; ++nj)
#pragma unroll
        for (int kk = 0; kk < 2; ++kk)
          acc[1][mi][nj] = __builtin_amdgcn_mfma_f32_16x16x32_bf16(a[mi][kk], b[nj][kk], acc[1][mi][nj], 0, 0, 0);
    __builtin_amdgcn_s_setprio(0);
    __builtin_amdgcn_s_barrier();
  }

  asm volatile("s_waitcnt vmcnt(0)" ::: "memory");   // drain clamped epilogue prefetches

  // ---- epilogue: bias + exact GELU, fp32 store ----
  float bcol[4];
#pragma unroll
  for (int ni = 0; ni < 4; ++ni)
    bcol[ni] = bias[col0 + (wni << 6) + ni * 16 + fr];

#pragma unroll
  for (int qm = 0; qm < 2; ++qm)
#pragma unroll
    for (int mi = 0; mi < 4; ++mi)
#pragma unroll
      for (int ni = 0; ni < 4; ++ni) {
        const int c = col0 + (wni << 6) + ni * 16 + fr;
#pragma unroll
        for (int j = 0; j < 4; ++j) {
          const int r = row0 + wmi * 128 + qm * 64 + mi * 16 + hi * 4 + j;
          float y = acc[qm][mi][ni][j] + bcol[ni];
          out[(size_t)r * HIDDEN + c] = 0.5f * y * (1.0f + erff(y * 0.70710678118654752f));
        }
      }
}

extern "C" void kernel_launch(void* const* d_in, const int* in_sizes, int n_in,
                              void* d_out, int out_size, void* d_ws, size_t ws_size,
                              hipStream_t stream) {
  const float* x     = (const float*)d_in[0];
  const float* gamma = (const float*)d_in[1];
  const float* beta  = (const float*)d_in[2];
  const float* W     = (const float*)d_in[3];
  const float* bias  = (const float*)d_in[4];
  float* out = (float*)d_out;

  unsigned short* xn = (unsigned short*)d_ws;
  unsigned short* wb = (unsigned short*)((char*)d_ws + (size_t)TOKENS * HIDDEN * 2);

  hipLaunchKernelGGL(wconv_kernel, dim3(1024), dim3(256), 0, stream, W, wb);
  hipLaunchKernelGGL(ln_kernel, dim3(TOKENS), dim3(256), 0, stream, x, gamma, beta, xn);
  hipLaunchKernelGGL(gemm_kernel, dim3((TOKENS / BM) * (HIDDEN / BN)), dim3(512), 0, stream,
                     xn, wb, bias, out);
}

// Round 3
// 176.244 us; speedup vs baseline: 1.2548x; 1.0710x over previous
//
#include <hip/hip_runtime.h>
#include <math.h>

#define TOKENS 16384
#define HIDDEN 2048
#define BM 256
#define BN 256
#define BK 64
#define NT (HIDDEN / BK)   // 32 K-tiles

typedef __attribute__((ext_vector_type(4))) float f32x4;
typedef __attribute__((ext_vector_type(8))) short s16x8;

__device__ __forceinline__ unsigned short f2bf(float f) {
  unsigned int u = __float_as_uint(f);
  u += 0x7fffu + ((u >> 16) & 1u);   // round-to-nearest-even
  return (unsigned short)(u >> 16);
}

// tanh-approx GELU via raw v_exp_f32 + v_rcp_f32.
// gelu(y) = y * sigmoid(1.5957691216*(y + 0.044715 y^3));
// exp2 constant folds log2(e): 1.5957691216 * 1.4426950409 = 2.3022082.
// |tanh-gelu - erf-gelu| <= ~1e-3, well under the 6.5e-2 threshold.
__device__ __forceinline__ float fast_gelu(float y) {
  float t = y * fmaf(y * y, 0.044715f, 1.0f);
  float e = __builtin_amdgcn_exp2f(-2.3022082f * t);
  return y * __builtin_amdgcn_rcpf(1.0f + e);
}

// ---------------- kernel 0: W fp32 -> bf16 ----------------
__global__ __launch_bounds__(256) void wconv_kernel(const float* __restrict__ W,
                                                    unsigned short* __restrict__ Wb) {
  const int n4 = (HIDDEN * HIDDEN) / 4;
  for (int i = blockIdx.x * 256 + threadIdx.x; i < n4; i += gridDim.x * 256) {
    float4 v = *(const float4*)(W + (size_t)i * 4);
    ushort4 o;
    o.x = f2bf(v.x); o.y = f2bf(v.y); o.z = f2bf(v.z); o.w = f2bf(v.w);
    *(ushort4*)(Wb + (size_t)i * 4) = o;
  }
}

// ---------------- kernel 1: LayerNorm fp32 -> bf16, one block per row ----------------
__global__ __launch_bounds__(256) void ln_kernel(const float* __restrict__ x,
                                                 const float* __restrict__ gamma,
                                                 const float* __restrict__ beta,
                                                 unsigned short* __restrict__ xn) {
  const int row = blockIdx.x;
  const int t = threadIdx.x;
  const int wave = t >> 6, lane = t & 63;
  const float* xr = x + (size_t)row * HIDDEN + t * 8;
  float4 v0 = *(const float4*)(xr);
  float4 v1 = *(const float4*)(xr + 4);
  float xv[8] = {v0.x, v0.y, v0.z, v0.w, v1.x, v1.y, v1.z, v1.w};

  float s = 0.f, ss = 0.f;
#pragma unroll
  for (int j = 0; j < 8; ++j) { s += xv[j]; ss = fmaf(xv[j], xv[j], ss); }

#pragma unroll
  for (int off = 32; off > 0; off >>= 1) {
    s += __shfl_xor(s, off, 64);
    ss += __shfl_xor(ss, off, 64);
  }
  __shared__ float rs[4], rss[4];
  if (lane == 0) { rs[wave] = s; rss[wave] = ss; }
  __syncthreads();
  s = rs[0] + rs[1] + rs[2] + rs[3];
  ss = rss[0] + rss[1] + rss[2] + rss[3];

  const float mean = s * (1.0f / HIDDEN);
  const float var = ss * (1.0f / HIDDEN) - mean * mean;
  const float rstd = rsqrtf(var + 1e-5f);

  float4 g0 = *(const float4*)(gamma + t * 8);
  float4 g1 = *(const float4*)(gamma + t * 8 + 4);
  float4 b0 = *(const float4*)(beta + t * 8);
  float4 b1 = *(const float4*)(beta + t * 8 + 4);
  float gv[8] = {g0.x, g0.y, g0.z, g0.w, g1.x, g1.y, g1.z, g1.w};
  float bv[8] = {b0.x, b0.y, b0.z, b0.w, b1.x, b1.y, b1.z, b1.w};

  union { unsigned short h[8]; uint4 q; } pk;
#pragma unroll
  for (int j = 0; j < 8; ++j)
    pk.h[j] = f2bf((xv[j] - mean) * rstd * gv[j] + bv[j]);
  *(uint4*)(xn + (size_t)row * HIDDEN + t * 8) = pk.q;
}

// ---------------- kernel 2: 256x256 8-phase bf16 GEMM + bias + fast GELU ----------------
// A[M,K] * B[N,K]^T. 512 threads = 8 waves (2M x 4N), per-wave output 128x64.
// LDS 128 KiB: 2 buf x {A,B} x 2 half x 2 quarter x 8KB. Quarter = 64 rows x 64 cols bf16.
// XOR swizzle byte ^= ((row&7)<<4) applied on global-gather side AND ds_read side.
// Counted vmcnt(4) once per K-tile; raw s_barrier; setprio around MFMA clusters.

#define GLOAD(gp, lp) __builtin_amdgcn_global_load_lds( \
    (const __attribute__((address_space(1))) unsigned int*)(gp), \
    (__attribute__((address_space(3))) unsigned int*)(lp), 16, 0, 0)

__global__ __launch_bounds__(512, 1) void gemm_kernel(const unsigned short* __restrict__ A,
                                                      const unsigned short* __restrict__ B,
                                                      const float* __restrict__ bias,
                                                      float* __restrict__ out) {
  __shared__ __attribute__((aligned(16))) char lds[131072];

  const int tid = threadIdx.x;
  const int lane = tid & 63;
  const int wave = tid >> 6;
  const int fr = lane & 15, hi = lane >> 4;

  // XCD-aware swizzle: 512 WGs, 512 % 8 == 0 -> bijective
  const int wg = blockIdx.x;
  const int swz = (wg & 7) * 64 + (wg >> 3);
  const int tm = swz >> 3, tn = swz & 7;   // 64 M-tiles x 8 N-tiles
  const int row0 = tm * BM, col0 = tn * BN;

  const int wmi = wave >> 2;        // wave M index (0..1)
  const int wni = wave & 3;         // wave N index (0..3)
  const int hB = wni >> 1, gB = wni & 1;

  // ---- staging geometry (per-lane gather, pre-swizzled source) ----
  const int rho = tid >> 3, sig = tid & 7;
  const int colgrp = ((sig ^ (rho & 7)) << 3);                 // k-element offset
  const unsigned short* Ap = A + (size_t)(row0 + rho) * HIDDEN + colgrp;
  const unsigned short* Bp = B + (size_t)(col0 + ((rho >> 5) << 6) + (rho & 31)) * HIDDEN + colgrp;
  const int ldsWaveOff = wave << 10;                            // 64 lanes * 16B

  // ---- ds_read per-lane constants (swizzled slot bytes for kk=0,1) ----
  const int s0 = ((hi ^ (fr & 7)) << 4);
  const int s1 = (((4 + hi) ^ (fr & 7)) << 4);
  const int aRowB = fr << 7;                        // fr*128
  const int bRowB = (((gB << 5) + fr) << 7);        // (gB*32+fr)*128

  auto stageA = [&](int tt, int bufd, int qm) {     // 2 calls: halves h=0,1 of quarter qm
    const int tc = tt < NT ? tt : NT - 1;
    const unsigned short* g = Ap + (size_t)(qm << 6) * HIDDEN + tc * BK;
    GLOAD(g, lds + ((((bufd << 2) | qm) << 13)) + ldsWaveOff);
    GLOAD(g + (size_t)128 * HIDDEN, lds + ((((bufd << 2) | 2 | qm) << 13)) + ldsWaveOff);
  };
  auto stageB = [&](int tt, int bufd, int qn) {
    const int tc = tt < NT ? tt : NT - 1;
    const unsigned short* g = Bp + (size_t)(qn << 5) * HIDDEN + tc * BK;
    GLOAD(g, lds + 65536 + ((((bufd << 2) | qn) << 13)) + ldsWaveOff);
    GLOAD(g + (size_t)128 * HIDDEN, lds + 65536 + ((((bufd << 2) | 2 | qn) << 13)) + ldsWaveOff);
  };

  f32x4 acc[2][4][4] = {};
  s16x8 a[4][2], b[2][2];

  // ---- prologue: tile0 fully + tile1's first 2 quarters, in steady-state age order ----
  stageA(0, 0, 0); stageB(0, 0, 1); stageA(0, 0, 1); stageB(0, 0, 0);
  stageA(1, 1, 0); stageB(1, 1, 1);
  asm volatile("s_waitcnt vmcnt(4)" ::: "memory");   // tile0's 8 calls landed
  __builtin_amdgcn_s_barrier();

  for (int t = 0; t < NT; ++t) {
    const int buf = t & 1;
    const char* Abase = lds + (((buf << 2) | (wmi << 1)) << 13);
    const char* Bbase = lds + 65536 + (((buf << 2) | (hB << 1)) << 13);

    // ===== p0: quadrant (qm=0, qn=0) =====
#pragma unroll
    for (int mi = 0; mi < 4; ++mi) {
      a[mi][0] = *(const s16x8*)(Abase + mi * 2048 + aRowB + s0);
      a[mi][1] = *(const s16x8*)(Abase + mi * 2048 + aRowB + s1);
    }
#pragma unroll
    for (int nj = 0; nj < 2; ++nj) {
      b[nj][0] = *(const s16x8*)(Bbase + nj * 2048 + bRowB + s0);
      b[nj][1] = *(const s16x8*)(Bbase + nj * 2048 + bRowB + s1);
    }
    stageA(t + 1, buf ^ 1, 1);
    asm volatile("s_waitcnt lgkmcnt(8)" ::: "memory");
    __builtin_amdgcn_s_barrier();
    asm volatile("s_waitcnt lgkmcnt(0)" ::: "memory");
    __builtin_amdgcn_s_setprio(1);
#pragma unroll
    for (int mi = 0; mi < 4; ++mi)
#pragma unroll
      for (int nj = 0; nj < 2; ++nj)
#pragma unroll
        for (int kk = 0; kk < 2; ++kk)
          acc[0][mi][nj] = __builtin_amdgcn_mfma_f32_16x16x32_bf16(a[mi][kk], b[nj][kk], acc[0][mi][nj], 0, 0, 0);
    __builtin_amdgcn_s_setprio(0);
    __builtin_amdgcn_s_barrier();

    // ===== p1: quadrant (qm=0, qn=1) — reuse a =====
#pragma unroll
    for (int nj = 0; nj < 2; ++nj) {
      b[nj][0] = *(const s16x8*)(Bbase + 8192 + nj * 2048 + bRowB + s0);
      b[nj][1] = *(const s16x8*)(Bbase + 8192 + nj * 2048 + bRowB + s1);
    }
    stageB(t + 1, buf ^ 1, 0);
    __builtin_amdgcn_s_barrier();
    asm volatile("s_waitcnt lgkmcnt(0)" ::: "memory");
    __builtin_amdgcn_s_setprio(1);
#pragma unroll
    for (int mi = 0; mi < 4; ++mi)
#pragma unroll
      for (int nj = 0; nj < 2; ++nj)
#pragma unroll
        for (int kk = 0; kk < 2; ++kk)
          acc[0][mi][2 + nj] = __builtin_amdgcn_mfma_f32_16x16x32_bf16(a[mi][kk], b[nj][kk], acc[0][mi][2 + nj], 0, 0, 0);
    __builtin_amdgcn_s_setprio(0);
    __builtin_amdgcn_s_barrier();

    // ===== p2: quadrant (qm=1, qn=1) — reuse b =====
#pragma unroll
    for (int mi = 0; mi < 4; ++mi) {
      a[mi][0] = *(const s16x8*)(Abase + 8192 + mi * 2048 + aRowB + s0);
      a[mi][1] = *(const s16x8*)(Abase + 8192 + mi * 2048 + aRowB + s1);
    }
    stageA(t + 2, buf, 0);
    asm volatile("s_waitcnt lgkmcnt(4)" ::: "memory");
    __builtin_amdgcn_s_barrier();
    asm volatile("s_waitcnt lgkmcnt(0)" ::: "memory");
    __builtin_amdgcn_s_setprio(1);
#pragma unroll
    for (int mi = 0; mi < 4; ++mi)
#pragma unroll
      for (int nj = 0; nj < 2; ++nj)
#pragma unroll
        for (int kk = 0; kk < 2; ++kk)
          acc[1][mi][2 + nj] = __builtin_amdgcn_mfma_f32_16x16x32_bf16(a[mi][kk], b[nj][kk], acc[1][mi][2 + nj], 0, 0, 0);
    __builtin_amdgcn_s_setprio(0);
    __builtin_amdgcn_s_barrier();

    // ===== p3: quadrant (qm=1, qn=0) — reuse a; K-tile boundary vmcnt =====
#pragma unroll
    for (int nj = 0; nj < 2; ++nj) {
      b[nj][0] = *(const s16x8*)(Bbase + nj * 2048 + bRowB + s0);
      b[nj][1] = *(const s16x8*)(Bbase + nj * 2048 + bRowB + s1);
    }
    stageB(t + 2, buf, 1);
    asm volatile("s_waitcnt vmcnt(4)" ::: "memory");   // counted: next tile fully landed, 4 in flight
    __builtin_amdgcn_s_barrier();
    asm volatile("s_waitcnt lgkmcnt(0)" ::: "memory");
    __builtin_amdgcn_s_setprio(1);
#pragma unroll
    for (int mi = 0; mi < 4; ++mi)
#pragma unroll
      for (int nj = 0; nj < 2; ++nj)
#pragma unroll
        for (int kk = 0; kk < 2; ++kk)
          acc[1][mi][nj] = __builtin_amdgcn_mfma_f32_16x16x32_bf16(a[mi][kk], b[nj][kk], acc[1][mi][nj], 0, 0, 0);
    __builtin_amdgcn_s_setprio(0);
    __builtin_amdgcn_s_barrier();
  }

  asm volatile("s_waitcnt vmcnt(0)" ::: "memory");   // drain clamped epilogue prefetches

  // ---- epilogue: bias + fast GELU, fp32 store ----
  float bcol[4];
#pragma unroll
  for (int ni = 0; ni < 4; ++ni)
    bcol[ni] = bias[col0 + (wni << 6) + ni * 16 + fr];

#pragma unroll
  for (int qm = 0; qm < 2; ++qm)
#pragma unroll
    for (int mi = 0; mi < 4; ++mi)
#pragma unroll
      for (int ni = 0; ni < 4; ++ni) {
        const int c = col0 + (wni << 6) + ni * 16 + fr;
#pragma unroll
        for (int j = 0; j < 4; ++j) {
          const int r = row0 + wmi * 128 + qm * 64 + mi * 16 + hi * 4 + j;
          float y = acc[qm][mi][ni][j] + bcol[ni];
          out[(size_t)r * HIDDEN + c] = fast_gelu(y);
        }
      }
}

extern "C" void kernel_launch(void* const* d_in, const int* in_sizes, int n_in,
                              void* d_out, int out_size, void* d_ws, size_t ws_size,
                              hipStream_t stream) {
  const float* x     = (const float*)d_in[0];
  const float* gamma = (const float*)d_in[1];
  const float* beta  = (const float*)d_in[2];
  const float* W     = (const float*)d_in[3];
  const float* bias  = (const float*)d_in[4];
  float* out = (float*)d_out;

  unsigned short* xn = (unsigned short*)d_ws;
  unsigned short* wb = (unsigned short*)((char*)d_ws + (size_t)TOKENS * HIDDEN * 2);

  hipLaunchKernelGGL(wconv_kernel, dim3(1024), dim3(256), 0, stream, W, wb);
  hipLaunchKernelGGL(ln_kernel, dim3(TOKENS), dim3(256), 0, stream, x, gamma, beta, xn);
  hipLaunchKernelGGL(gemm_kernel, dim3((TOKENS / BM) * (HIDDEN / BN)), dim3(512), 0, stream,
                     xn, wb, bias, out);
}